// Round 1
// baseline (181.326 us; speedup 1.0000x reference)
//
#include <hip/hip_runtime.h>
#include <hip/hip_bf16.h>

#define D_DIM   128
#define MT      32        // node rows per block-iteration (6250 tiles exactly)
#define NBLOCKS 768       // persistent: 3 blocks/CU x 256 CUs
#define NTHR    256       // 4 waves

typedef __attribute__((ext_vector_type(8))) short bf16x8;
typedef __attribute__((ext_vector_type(4))) float f32x4;

__device__ __forceinline__ unsigned short f2bf(float f) {
    return __builtin_bit_cast(unsigned short, __float2bfloat16(f));
}

// XOR-swizzled offset (in shorts) into a [rows][128] bf16 LDS tile.
// 16B chunks permuted per row: conflict-free ds_read_b128, zero padding.
__device__ __forceinline__ int sw_off(int row, int col) {
    return row * 128 + ((((col >> 3) ^ (row & 15)) << 3) | (col & 7));
}

// one-time: load a B-fragment (8 consecutive k at row j) straight from global fp32
__device__ __forceinline__ bf16x8 load_wfrag(const float* __restrict__ w, int j, int kb) {
    const float4 lo = *(const float4*)(w + j * D_DIM + kb);
    const float4 hi = *(const float4*)(w + j * D_DIM + kb + 4);
    bf16x8 r;
    r[0] = (short)f2bf(lo.x); r[1] = (short)f2bf(lo.y);
    r[2] = (short)f2bf(lo.z); r[3] = (short)f2bf(lo.w);
    r[4] = (short)f2bf(hi.x); r[5] = (short)f2bf(hi.y);
    r[6] = (short)f2bf(hi.z); r[7] = (short)f2bf(hi.w);
    return r;
}

__global__ __launch_bounds__(NTHR, 3)
void ctx_encoder(const int* __restrict__ nodes,
                 const float* __restrict__ c2e,
                 const float* __restrict__ w1,
                 const float* __restrict__ b1,
                 const float* __restrict__ w2,
                 const float* __restrict__ b2,
                 float* __restrict__ out,
                 int N) {
    __shared__ unsigned short sA[MT * 128];   // 8 KB gather/A tile
    __shared__ unsigned short sH[MT * 128];   // 8 KB h tile  -> 16 KB total

    const int t    = threadIdx.x;
    const int lane = t & 63;
    const int wave = t >> 6;       // 0..3: owns output cols wave*32 .. wave*32+31
    const int cl   = lane & 15;
    const int quad = lane >> 4;

    // gather role: thread t fetches 16B slices of row grow0 (8 threads/row)
    const int grow0 = t >> 3;      // 0..31
    const int gc    = t & 7;

    // ---- weights -> registers, held for the whole persistent loop ----
    // wB[c][ks]: rows j=(2*wave+c)*16+cl of W, k = ks*32+quad*8 .. +7
    bf16x8 wB1[2][4], wB2[2][4];
    float bias1[2], bias2[2];
    #pragma unroll
    for (int c = 0; c < 2; ++c) {
        const int j = (wave * 2 + c) * 16 + cl;
        bias1[c] = b1[j];
        bias2[c] = b2[j];
        #pragma unroll
        for (int ks = 0; ks < 4; ++ks) {
            const int kb = ks * 32 + quad * 8;
            wB1[c][ks] = load_wfrag(w1, j, kb);
            wB2[c][ks] = load_wfrag(w2, j, kb);
        }
    }

    const int nTiles = (N + MT - 1) / MT;
    int tl = blockIdx.x;

    // ---- prologue: gather tile0, prefetch next idx ----
    int r0 = tl * MT + grow0;  r0 = r0 < N ? r0 : N - 1;
    int idx_cur = nodes[r0];
    float4 g[4];
    {
        const float* rp = c2e + (size_t)idx_cur * D_DIM + gc * 4;
        #pragma unroll
        for (int i = 0; i < 4; ++i)
            g[i] = *(const float4*)(rp + i * 32);   // 8x128B contiguous runs per instr
    }
    int idx_nxt = 0;
    if (tl + NBLOCKS < nTiles) {
        int r1 = (tl + NBLOCKS) * MT + grow0;  r1 = r1 < N ? r1 : N - 1;
        idx_nxt = nodes[r1];
    }

    while (tl < nTiles) {
        // ---- s1: gathered rows -> bf16 -> sA (swizzled) ----
        // prev iter's hF reads / aF reads are all older than this point's B1,
        // so 2 barriers/tile suffice with split A/h buffers.
        #pragma unroll
        for (int i = 0; i < 4; ++i) {
            ushort4 b;
            b.x = f2bf(g[i].x); b.y = f2bf(g[i].y);
            b.z = f2bf(g[i].z); b.w = f2bf(g[i].w);
            *(ushort4*)&sA[sw_off(grow0, gc * 4 + i * 32)] = b;
        }
        __syncthreads();   // B1: sA ready (and all prev-iter sH reads complete)

        // ---- s2: A-fragments (shared by all 4 waves) ----
        bf16x8 aF[2][4];
        #pragma unroll
        for (int m = 0; m < 2; ++m)
            #pragma unroll
            for (int ks = 0; ks < 4; ++ks)
                aF[m][ks] = *(const bf16x8*)&sA[sw_off(m * 16 + cl, ks * 32 + quad * 8)];

        // ---- s3: issue next tile's gather (hides under both MFMA phases) ----
        const int tn = tl + NBLOCKS;
        if (tn < nTiles) {
            const float* rp = c2e + (size_t)idx_nxt * D_DIM + gc * 4;
            #pragma unroll
            for (int i = 0; i < 4; ++i)
                g[i] = *(const float4*)(rp + i * 32);
            if (tn + NBLOCKS < nTiles) {
                int rn = (tn + NBLOCKS) * MT + grow0;  rn = rn < N ? rn : N - 1;
                idx_nxt = nodes[rn];
            }
        }

        // ---- s4: layer 1 (weights from registers) -> h into sH ----
        #pragma unroll
        for (int m = 0; m < 2; ++m) {
            #pragma unroll
            for (int c = 0; c < 2; ++c) {
                f32x4 acc = {0.f, 0.f, 0.f, 0.f};
                #pragma unroll
                for (int ks = 0; ks < 4; ++ks)
                    acc = __builtin_amdgcn_mfma_f32_16x16x32_bf16(aF[m][ks], wB1[c][ks], acc, 0, 0, 0);
                const int j = (wave * 2 + c) * 16 + cl;
                #pragma unroll
                for (int r = 0; r < 4; ++r) {
                    float h = acc[r] + bias1[c];
                    h = h > 0.f ? h : 0.f;
                    sH[sw_off(m * 16 + quad * 4 + r, j)] = f2bf(h);
                }
            }
        }
        __syncthreads();   // B2: sH ready (and all aF reads of sA complete)

        // ---- s5: h-fragments ----
        bf16x8 hF[2][4];
        #pragma unroll
        for (int m = 0; m < 2; ++m)
            #pragma unroll
            for (int ks = 0; ks < 4; ++ks)
                hF[m][ks] = *(const bf16x8*)&sH[sw_off(m * 16 + cl, ks * 32 + quad * 8)];

        // ---- s6: layer 2 (weights from registers) + nontemporal store ----
        const size_t obase = (size_t)tl * MT;
        #pragma unroll
        for (int m = 0; m < 2; ++m) {
            #pragma unroll
            for (int c = 0; c < 2; ++c) {
                f32x4 acc = {0.f, 0.f, 0.f, 0.f};
                #pragma unroll
                for (int ks = 0; ks < 4; ++ks)
                    acc = __builtin_amdgcn_mfma_f32_16x16x32_bf16(hF[m][ks], wB2[c][ks], acc, 0, 0, 0);
                const int j = (wave * 2 + c) * 16 + cl;
                #pragma unroll
                for (int r = 0; r < 4; ++r) {
                    float o = acc[r] + bias2[c];
                    o = o > 0.f ? o : 0.f;
                    const long grow = (long)(obase + m * 16 + quad * 4 + r);
                    if (grow < N)
                        __builtin_nontemporal_store(o, &out[(size_t)grow * D_DIM + j]);
                }
            }
        }

        tl += NBLOCKS;
    }
}

extern "C" void kernel_launch(void* const* d_in, const int* in_sizes, int n_in,
                              void* d_out, int out_size, void* d_ws, size_t ws_size,
                              hipStream_t stream) {
    const int*   nodes = (const int*)d_in[0];
    const float* c2e   = (const float*)d_in[1];
    const float* w1    = (const float*)d_in[2];
    const float* b1    = (const float*)d_in[3];
    const float* w2    = (const float*)d_in[4];
    const float* b2    = (const float*)d_in[5];
    float* out = (float*)d_out;
    const int N = in_sizes[0];

    ctx_encoder<<<dim3(NBLOCKS), dim3(NTHR), 0, stream>>>(nodes, c2e, w1, b1, w2, b2, out, N);
}

// Round 2
// 165.576 us; speedup vs baseline: 1.0951x; 1.0951x over previous
//
#include <hip/hip_runtime.h>
#include <hip/hip_bf16.h>

#define D_DIM   128
#define MT      64        // node rows per block-iteration (3125 tiles exactly)
#define NBLOCKS 512       // persistent: 2 blocks/CU x 256 CUs
#define NTHR    512       // 8 waves; wave w owns output cols w*16 .. w*16+15

typedef __attribute__((ext_vector_type(8))) short bf16x8;
typedef __attribute__((ext_vector_type(4))) float f32x4;

__device__ __forceinline__ unsigned short f2bf(float f) {
    return __builtin_bit_cast(unsigned short, __float2bfloat16(f));
}

// XOR-swizzled offset (in shorts) into a [rows][128] bf16 LDS tile.
// 16B chunks permuted per row: conflict-free ds_read_b128, zero padding.
__device__ __forceinline__ int sw_off(int row, int col) {
    return row * 128 + ((((col >> 3) ^ (row & 15)) << 3) | (col & 7));
}

// one-time: load a B-fragment (8 consecutive k at row j) straight from global fp32
__device__ __forceinline__ bf16x8 load_wfrag(const float* __restrict__ w, int j, int kb) {
    const float4 lo = *(const float4*)(w + j * D_DIM + kb);
    const float4 hi = *(const float4*)(w + j * D_DIM + kb + 4);
    bf16x8 r;
    r[0] = (short)f2bf(lo.x); r[1] = (short)f2bf(lo.y);
    r[2] = (short)f2bf(lo.z); r[3] = (short)f2bf(lo.w);
    r[4] = (short)f2bf(hi.x); r[5] = (short)f2bf(hi.y);
    r[6] = (short)f2bf(hi.z); r[7] = (short)f2bf(hi.w);
    return r;
}

// launch_bounds(512,4): 4 waves/EU min -> regalloc capped at 128 VGPR
// -> 2 blocks/CU, 16 waves/CU guaranteed (same TLP as round-0 best).
__global__ __launch_bounds__(NTHR, 4)
void ctx_encoder(const int* __restrict__ nodes,
                 const float* __restrict__ c2e,
                 const float* __restrict__ w1,
                 const float* __restrict__ b1,
                 const float* __restrict__ w2,
                 const float* __restrict__ b2,
                 float* __restrict__ out,
                 int N) {
    __shared__ unsigned short sA[MT * 128];   // 16 KB gather/A tile
    __shared__ unsigned short sH[MT * 128];   // 16 KB h tile -> 32 KB total

    const int t    = threadIdx.x;
    const int lane = t & 63;
    const int wave = t >> 6;       // ct-slab 0..7: cols wave*16 .. wave*16+15
    const int cl   = lane & 15;
    const int quad = lane >> 4;
    const int j    = wave * 16 + cl;   // this lane's output column

    // gather role: thread t fetches 16B slices of row grow0 (8 threads/row)
    const int grow0 = t >> 3;      // 0..63
    const int gc    = t & 7;

    // ---- weights -> registers, held for the whole persistent loop ----
    // wB[ks]: row j of W, k = ks*32+quad*8 .. +7  (8 frags = 32 VGPRs total)
    bf16x8 wB1[4], wB2[4];
    #pragma unroll
    for (int ks = 0; ks < 4; ++ks) {
        const int kb = ks * 32 + quad * 8;
        wB1[ks] = load_wfrag(w1, j, kb);
        wB2[ks] = load_wfrag(w2, j, kb);
    }
    const float bias1 = b1[j];
    const float bias2 = b2[j];

    const int nTiles = (N + MT - 1) / MT;
    int tl = blockIdx.x;

    // ---- prologue: gather tile0, prefetch next idx ----
    int r0 = tl * MT + grow0;  r0 = r0 < N ? r0 : N - 1;
    int idx_cur = nodes[r0];
    float4 g[4];
    {
        const float* rp = c2e + (size_t)idx_cur * D_DIM + gc * 4;
        #pragma unroll
        for (int i = 0; i < 4; ++i)
            g[i] = *(const float4*)(rp + i * 32);   // 8x128B contiguous runs per instr
    }
    int idx_nxt = 0;
    if (tl + NBLOCKS < nTiles) {
        int r1 = (tl + NBLOCKS) * MT + grow0;  r1 = r1 < N ? r1 : N - 1;
        idx_nxt = nodes[r1];
    }

    while (tl < nTiles) {
        // ---- s1: gathered rows -> bf16 -> sA (swizzled) ----
        #pragma unroll
        for (int i = 0; i < 4; ++i) {
            ushort4 b;
            b.x = f2bf(g[i].x); b.y = f2bf(g[i].y);
            b.z = f2bf(g[i].z); b.w = f2bf(g[i].w);
            *(ushort4*)&sA[sw_off(grow0, gc * 4 + i * 32)] = b;
        }
        __syncthreads();   // B1: sA ready; prev-iter sH reads complete

        // ---- s3: issue next tile's gather (hides under both MFMA phases) ----
        const int tn = tl + NBLOCKS;
        if (tn < nTiles) {
            const float* rp = c2e + (size_t)idx_nxt * D_DIM + gc * 4;
            #pragma unroll
            for (int i = 0; i < 4; ++i)
                g[i] = *(const float4*)(rp + i * 32);
            if (tn + NBLOCKS < nTiles) {
                int rn = (tn + NBLOCKS) * MT + grow0;  rn = rn < N ? rn : N - 1;
                idx_nxt = nodes[rn];
            }
        }

        // ---- s4: layer 1 (weights in registers) -> h into sH ----
        #pragma unroll
        for (int m = 0; m < 4; ++m) {
            bf16x8 aF[4];
            #pragma unroll
            for (int ks = 0; ks < 4; ++ks)
                aF[ks] = *(const bf16x8*)&sA[sw_off(m * 16 + cl, ks * 32 + quad * 8)];
            f32x4 acc = {0.f, 0.f, 0.f, 0.f};
            #pragma unroll
            for (int ks = 0; ks < 4; ++ks)
                acc = __builtin_amdgcn_mfma_f32_16x16x32_bf16(aF[ks], wB1[ks], acc, 0, 0, 0);
            #pragma unroll
            for (int r = 0; r < 4; ++r) {
                float h = acc[r] + bias1;
                h = h > 0.f ? h : 0.f;
                sH[sw_off(m * 16 + quad * 4 + r, j)] = f2bf(h);
            }
        }
        __syncthreads();   // B2: sH ready; all aF reads of sA complete

        // ---- s6: layer 2 (weights in registers) + store ----
        const size_t obase = (size_t)tl * MT;
        #pragma unroll
        for (int m = 0; m < 4; ++m) {
            bf16x8 hF[4];
            #pragma unroll
            for (int ks = 0; ks < 4; ++ks)
                hF[ks] = *(const bf16x8*)&sH[sw_off(m * 16 + cl, ks * 32 + quad * 8)];
            f32x4 acc = {0.f, 0.f, 0.f, 0.f};
            #pragma unroll
            for (int ks = 0; ks < 4; ++ks)
                acc = __builtin_amdgcn_mfma_f32_16x16x32_bf16(hF[ks], wB2[ks], acc, 0, 0, 0);
            #pragma unroll
            for (int r = 0; r < 4; ++r) {
                float o = acc[r] + bias2;
                o = o > 0.f ? o : 0.f;
                const long grow = (long)(obase + m * 16 + quad * 4 + r);
                if (grow < N)
                    out[(size_t)grow * D_DIM + j] = o;
            }
        }

        tl += NBLOCKS;
    }
}

extern "C" void kernel_launch(void* const* d_in, const int* in_sizes, int n_in,
                              void* d_out, int out_size, void* d_ws, size_t ws_size,
                              hipStream_t stream) {
    const int*   nodes = (const int*)d_in[0];
    const float* c2e   = (const float*)d_in[1];
    const float* w1    = (const float*)d_in[2];
    const float* b1    = (const float*)d_in[3];
    const float* w2    = (const float*)d_in[4];
    const float* b2    = (const float*)d_in[5];
    float* out = (float*)d_out;
    const int N = in_sizes[0];

    ctx_encoder<<<dim3(NBLOCKS), dim3(NTHR), 0, stream>>>(nodes, c2e, w1, b1, w2, b2, out, N);
}